// Round 1
// baseline (57.236 us; speedup 1.0000x reference)
//
#include <hip/hip_runtime.h>

// Elementwise fused forward:
//   act = sigmoid(x*cw + cb)
//   h   = relu(act*w1 + b1); h = relu(h*w2 + b2)
//   out = 0.5*(sigmoid(h*w30 + b30) + sigmoid(h*w31 + b31))
// Memory-bound: 128 MiB in + 128 MiB out. float4 vectorized grid-stride loop.

__device__ __forceinline__ float fast_sigmoid(float x) {
    return 1.0f / (1.0f + __expf(-x));
}

__global__ __launch_bounds__(256) void hybridconv_kernel(
    const float4* __restrict__ data4,
    float4* __restrict__ out4,
    const float* __restrict__ cw_p, const float* __restrict__ cb_p,
    const float* __restrict__ w1_p, const float* __restrict__ b1_p,
    const float* __restrict__ w2_p, const float* __restrict__ b2_p,
    const float* __restrict__ w3_p, const float* __restrict__ b3_p,
    int n4)
{
    // Scalar params: same address across the wave -> one cached request each.
    const float cw  = *cw_p,   cb  = *cb_p;
    const float w1  = *w1_p,   b1  = *b1_p;
    const float w2  = *w2_p,   b2  = *b2_p;
    const float w30 = w3_p[0], w31 = w3_p[1];
    const float b30 = b3_p[0], b31 = b3_p[1];

    const int stride = gridDim.x * blockDim.x;
    for (int i = blockIdx.x * blockDim.x + threadIdx.x; i < n4; i += stride) {
        float4 v = data4[i];
        float x[4] = {v.x, v.y, v.z, v.w};
        float r[4];
#pragma unroll
        for (int j = 0; j < 4; ++j) {
            float act = fast_sigmoid(fmaf(x[j], cw, cb));
            float h   = fmaxf(fmaf(act, w1, b1), 0.0f);
            h         = fmaxf(fmaf(h,   w2, b2), 0.0f);
            float s0  = fast_sigmoid(fmaf(h, w30, b30));
            float s1  = fast_sigmoid(fmaf(h, w31, b31));
            r[j] = 0.5f * (s0 + s1);
        }
        out4[i] = make_float4(r[0], r[1], r[2], r[3]);
    }
}

extern "C" void kernel_launch(void* const* d_in, const int* in_sizes, int n_in,
                              void* d_out, int out_size, void* d_ws, size_t ws_size,
                              hipStream_t stream) {
    const float* data = (const float*)d_in[0];
    const float* cw   = (const float*)d_in[1];
    const float* cb   = (const float*)d_in[2];
    const float* w1   = (const float*)d_in[3];
    const float* b1   = (const float*)d_in[4];
    const float* w2   = (const float*)d_in[5];
    const float* b2   = (const float*)d_in[6];
    const float* w3   = (const float*)d_in[7];
    const float* b3   = (const float*)d_in[8];
    float* out = (float*)d_out;

    const int n = in_sizes[0];        // 33,554,432 (divisible by 4)
    const int n4 = n / 4;

    const int block = 256;
    int grid = (n4 + block - 1) / block;
    if (grid > 2048) grid = 2048;     // grid-stride the rest (G11)

    hybridconv_kernel<<<grid, block, 0, stream>>>(
        (const float4*)data, (float4*)out,
        cw, cb, w1, b1, w2, b2, w3, b3, n4);
}